// Round 18
// baseline (425.169 us; speedup 1.0000x reference)
//
#include <hip/hip_runtime.h>

#define N_NODES 16384
#define KDIM    16384
#define E_EDGES 524288
#define H1DIM   200
#define H2DIM   8

#define BM 128
#define BK 32
#define KSPLIT 4
#define KLEN 4096       // KDIM / KSPLIT
#define NT 128          // KLEN / BK
#define H1P_STRIDE (N_NODES * H1DIM)   // floats per K-split partial (compact, no pad)

typedef __attribute__((ext_vector_type(8))) short bf16x8;
typedef __attribute__((ext_vector_type(4))) float fx4;
typedef __attribute__((ext_vector_type(4))) unsigned int ux4;
typedef __attribute__((ext_vector_type(2))) unsigned int ux2;

__device__ __forceinline__ unsigned short f2bf(float f) {
  unsigned int u = __builtin_bit_cast(unsigned int, f);
  return (unsigned short)((u + 0x7FFFu + ((u >> 16) & 1u)) >> 16);  // RNE
}
__device__ __forceinline__ unsigned int pk2(float a, float b) {
  return (unsigned int)f2bf(a) | ((unsigned int)f2bf(b) << 16);
}
__device__ __forceinline__ float bf2f(unsigned int u) {
  return __builtin_bit_cast(float, u << 16);
}

// ---------------- W1 pack (coalesced) + edge-degree atomics + per-edge rank (R17 verbatim) ----------------

__global__ void k_packdeg(const float* __restrict__ W1, unsigned short* __restrict__ Wt,
                          const int* __restrict__ ei, const float* __restrict__ ew,
                          float* deg, int* cnt, int* __restrict__ rank) {
  int n = threadIdx.x;            // 0..255
  int k8 = blockIdx.x;            // 0..2047
  int e = k8 * 256 + n;
  int c = ei[E_EDGES + e];
  rank[e] = atomicAdd(&cnt[c], 1);
  atomicAdd(&deg[c], ew[e]);
  unsigned short v[8];
  if (n < H1DIM) {
    const float* base = W1 + (size_t)(k8 * 8) * H1DIM + n;
#pragma unroll
    for (int i = 0; i < 8; ++i) v[i] = f2bf(base[(size_t)i * H1DIM]);
  } else {
#pragma unroll
    for (int i = 0; i < 8; ++i) v[i] = 0;
  }
  ux4 o;
  o[0] = (unsigned int)v[0] | ((unsigned int)v[1] << 16);
  o[1] = (unsigned int)v[2] | ((unsigned int)v[3] << 16);
  o[2] = (unsigned int)v[4] | ((unsigned int)v[5] << 16);
  o[3] = (unsigned int)v[6] | ((unsigned int)v[7] << 16);
  *(ux4*)(Wt + (size_t)k8 * 2048 + n * 8) = o;
}

// scan over cnt -> off (R17 verbatim)
__global__ void k_scan(const int* __restrict__ cnt, int* __restrict__ off) {
  __shared__ int s[1024];
  int t = threadIdx.x;
  int base = t * 16;
  int loc[16]; int sum = 0;
#pragma unroll
  for (int i = 0; i < 16; ++i) { loc[i] = cnt[base + i]; sum += loc[i]; }
  s[t] = sum; __syncthreads();
  for (int d = 1; d < 1024; d <<= 1) {
    int v = (t >= d) ? s[t - d] : 0;
    __syncthreads();
    s[t] += v;
    __syncthreads();
  }
  int run = (t == 0) ? 0 : s[t - 1];
#pragma unroll
  for (int i = 0; i < 16; ++i) { off[base + i] = run; run += loc[i]; }
  if (t == 1023) off[N_NODES] = run;
}

// atomic-free scatter (R17 verbatim)
__global__ void k_scatter(const int* __restrict__ ei, const float* __restrict__ ew,
                          const float* __restrict__ deg, const int* __restrict__ off,
                          const int* __restrict__ rank,
                          int* __restrict__ r2, float* __restrict__ w2) {
  int e = blockIdx.x * 256 + threadIdx.x;
  if (e < E_EDGES) {
    int r = ei[e], c = ei[E_EDGES + e];
    float w = rsqrtf(deg[r] + 1.0f) * ew[e] * rsqrtf(deg[c] + 1.0f);
    int p = off[c] + rank[e];
    r2[p] = r; w2[p] = w;
  }
}

// ---------------- GEMM1 (R17 schedule verbatim; A loads + C stores NON-TEMPORAL) ----------------
// A is stream-once: nt keeps it from evicting the L2-resident B-slice (the suspected
// source of gemm1's 40 us above HBM floor). Zero correctness impact (pure cache hint).

#define LOADA(KT, AI)                                                   \
  { const fx4* _p = (const fx4*)(xp0 + (KT) * BK);                      \
    aR[AI][0] = __builtin_nontemporal_load(_p);                         \
    aR[AI][1] = __builtin_nontemporal_load(_p + 1); }

#define STAGEB(BUF, KT)                                                                  \
  { const unsigned short* _s = wbase + (size_t)(KT) * 8192 + (size_t)t * 8;              \
    char* _d = ldsB + (BUF) * 16384 + wv * 1024;                                         \
    __builtin_amdgcn_global_load_lds((const __attribute__((address_space(1))) void*)(_s),        (__attribute__((address_space(3))) void*)(_d),        16, 0, 0); \
    __builtin_amdgcn_global_load_lds((const __attribute__((address_space(1))) void*)(_s + 4096), (__attribute__((address_space(3))) void*)(_d + 8192), 16, 0, 0); }

#define WRITEA(AI)                                          \
  { ux4 _dv;                                                \
    _dv[0] = pk2(aR[AI][0][0], aR[AI][0][1]);               \
    _dv[1] = pk2(aR[AI][0][2], aR[AI][0][3]);               \
    _dv[2] = pk2(aR[AI][1][0], aR[AI][1][1]);               \
    _dv[3] = pk2(aR[AI][1][2], aR[AI][1][3]);               \
    *(ux4*)(ldsA + (AI) * 8192 + ((akblk * 128 + am) << 4)) = _dv; }

#define COMPUTE(BUF)                                                                     \
  { const char* _pa = ldsA + (BUF) * 8192;                                               \
    const char* _pb = ldsB + (BUF) * 16384;                                              \
    bf16x8 _af[4], _bf[4];                                                               \
    _Pragma("unroll")                                                                    \
    for (int mi = 0; mi < 4; ++mi)                                                       \
      _af[mi] = *(const bf16x8*)(_pa + ((g * 128 + wm * 64 + mi * 16 + l15) << 4));      \
    _Pragma("unroll")                                                                    \
    for (int ni = 0; ni < 4; ++ni)                                                       \
      _bf[ni] = *(const bf16x8*)(_pb + ((g * 256 + wn * 64 + ni * 16 + l15) << 4));      \
    _Pragma("unroll")                                                                    \
    for (int mi = 0; mi < 4; ++mi)                                                       \
      _Pragma("unroll")                                                                  \
      for (int ni = 0; ni < 4; ++ni)                                                     \
        acc[mi][ni] = __builtin_amdgcn_mfma_f32_16x16x32_bf16(_af[mi], _bf[ni], acc[mi][ni], 0, 0, 0); }

#define SYNC_VM(N)                                          \
  __builtin_amdgcn_sched_barrier(0);                        \
  asm volatile("s_waitcnt vmcnt(" #N ")" ::: "memory");     \
  asm volatile("s_waitcnt lgkmcnt(0)" ::: "memory");        \
  __builtin_amdgcn_s_barrier();                             \
  __builtin_amdgcn_sched_barrier(0);

#define GSTEP(KT, PAR)                 \
  STAGEB((PAR) ^ 1, (KT) + 1)          \
  __builtin_amdgcn_sched_barrier(0);   \
  LOADA((KT) + 2, PAR)                 \
  __builtin_amdgcn_sched_barrier(0);   \
  COMPUTE(PAR)                         \
  WRITEA((PAR) ^ 1)                    \
  SYNC_VM(2)

__launch_bounds__(512, 4)
__global__ void k_gemm1(const float* __restrict__ x, const unsigned short* __restrict__ Wt,
                        float* __restrict__ h1p) {
  __shared__ char lds[49152];       // A: [2][8192] @0, B: [2][16384] @16384
  const int t = threadIdx.x;
  const int wv = t >> 6;
  const int wm = wv >> 2, wn = wv & 3;
  const int ln = t & 63;
  const int g = ln >> 4, l15 = ln & 15;
  const int bid = blockIdx.x;
  const int ks = bid & 3;
  const size_t m0 = (size_t)(bid >> 2) * BM;
  const int k0 = ks * KLEN;

  const int am = t >> 2;
  const int akblk = t & 3;
  const float* xp0 = x + (m0 + am) * (size_t)KDIM + k0 + akblk * 8;
  const unsigned short* wbase = Wt + (size_t)k0 * 256;

  char* ldsA = lds;
  char* ldsB = lds + 16384;

  fx4 acc[4][4] = {};
  fx4 aR[2][2];

  LOADA(0, 0)
  LOADA(1, 1)
  STAGEB(0, 0)
  WRITEA(0)
  SYNC_VM(0)

  for (int kt = 0; kt < NT - 2; kt += 2) {
    GSTEP(kt + 0, 0)
    GSTEP(kt + 1, 1)
  }

  STAGEB(1, NT - 1)
  __builtin_amdgcn_sched_barrier(0);
  COMPUTE(0)
  WRITEA(1)
  SYNC_VM(0)
  COMPUTE(1)

  // compact C-write: only cols < 200; non-temporal (consumed once by k_reduce)
  float* outp = h1p + (size_t)ks * H1P_STRIDE;
#pragma unroll
  for (int mi = 0; mi < 4; ++mi)
#pragma unroll
    for (int ni = 0; ni < 4; ++ni) {
      int col = wn * 64 + ni * 16 + l15;
      if (col < H1DIM) {
#pragma unroll
        for (int r = 0; r < 4; ++r)
          __builtin_nontemporal_store(acc[mi][ni][r],
              &outp[(m0 + wm * 64 + mi * 16 + g * 4 + r) * H1DIM + col]);
      }
    }
}

// ---------------- reduce: linear stream; h1p reads non-temporal ----------------

__global__ void k_reduce(const float* __restrict__ h1p, unsigned short* __restrict__ h1b) {
  int i = blockIdx.x * 256 + threadIdx.x;   // < 819200 fx4 items
  const fx4* a = (const fx4*)h1p;
  fx4 v = __builtin_nontemporal_load(a + i);
  v += __builtin_nontemporal_load(a + i + 819200);
  v += __builtin_nontemporal_load(a + i + 1638400);
  v += __builtin_nontemporal_load(a + i + 2457600);
  ux2 o;
  o[0] = pk2(v[0], v[1]);
  o[1] = pk2(v[2], v[3]);
  *(ux2*)(h1b + (size_t)i * 4) = o;
}

// ---------------- layer-1 agg + bias + relu + layer-2 linear (R17 verbatim) ----------------

__global__ void k_agg1(const unsigned short* __restrict__ h1b, const int* __restrict__ r2,
                       const float* __restrict__ w2, const int* __restrict__ off,
                       const float* __restrict__ deg, const float* __restrict__ b1,
                       const float* __restrict__ W2, float* __restrict__ g) {
  __shared__ float sh[H1DIM];
  __shared__ float w2s[H1DIM * H2DIM];
  __shared__ float red[256];
  int c = blockIdx.x;
  int t = threadIdx.x;
  if (t < H1DIM) {
    int p0 = off[c], p1 = off[c + 1];
    float acc = 0.0f;
    int p = p0;
    for (; p + 8 <= p1; p += 8) {       // 8-way unroll: 8 row-gathers in flight
      float a0 = 0.f, a1 = 0.f;
#pragma unroll
      for (int u = 0; u < 8; ++u) {
        int rr = r2[p + u];
        float ww = w2[p + u];
        float vv = bf2f((unsigned int)h1b[(size_t)rr * H1DIM + t]);
        if (u & 1) a1 += ww * vv; else a0 += ww * vv;
      }
      acc += a0 + a1;
    }
    for (; p < p1; ++p)
      acc += w2[p] * bf2f((unsigned int)h1b[(size_t)r2[p] * H1DIM + t]);
    float d2 = 1.0f / (deg[c] + 1.0f);    // dinv^2 exactly
    acc += d2 * bf2f((unsigned int)h1b[(size_t)c * H1DIM + t]);
    sh[t] = fmaxf(acc + b1[t], 0.0f);
  } else {
    for (int i = t - H1DIM; i < H1DIM * H2DIM; i += 256 - H1DIM) w2s[i] = W2[i];
  }
  __syncthreads();
  int jo = t & 7, kc = t >> 3;
  float part = 0.0f;
  for (int k = kc; k < H1DIM; k += 32) part += sh[k] * w2s[k * 8 + jo];
  red[t] = part;
  __syncthreads();
#pragma unroll
  for (int s = 16; s >= 1; s >>= 1) {
    if (kc < s) red[t] += red[t + s * 8];
    __syncthreads();
  }
  if (t < 8) g[(size_t)c * 8 + t] = red[t];
}

// ---------------- layer-2 aggregation + bias (R17 verbatim) ----------------

__global__ void k_agg2(const float* __restrict__ g, const int* __restrict__ r2,
                       const float* __restrict__ w2, const int* __restrict__ off,
                       const float* __restrict__ deg, const float* __restrict__ b2,
                       float* __restrict__ out) {
  int t = threadIdx.x;
  int c = blockIdx.x * 32 + (t >> 3), j = t & 7;
  int p0 = off[c], p1 = off[c + 1];
  float acc = 0.0f;
  for (int p = p0; p < p1; ++p) acc += w2[p] * g[(size_t)r2[p] * 8 + j];
  float d2 = 1.0f / (deg[c] + 1.0f);
  out[(size_t)c * 8 + j] = acc + d2 * g[(size_t)c * 8 + j] + b2[j];
}

// ---------------- launch ----------------

extern "C" void kernel_launch(void* const* d_in, const int* in_sizes, int n_in,
                              void* d_out, int out_size, void* d_ws, size_t ws_size,
                              hipStream_t stream) {
  (void)in_sizes; (void)n_in; (void)out_size; (void)ws_size;
  const float* x  = (const float*)d_in[0];
  const int*   ei = (const int*)d_in[1];
  const float* ew = (const float*)d_in[2];
  const float* W1 = (const float*)d_in[3];
  const float* b1 = (const float*)d_in[4];
  const float* W2 = (const float*)d_in[5];
  const float* b2 = (const float*)d_in[6];
  float* out = (float*)d_out;
  char* ws = (char*)d_ws;

  float* deg    = (float*)(ws + 0);          // 64 KiB  } contiguous 128 KiB,
  int*   cnt    = (int*)  (ws + 65536);      // 64 KiB  } zeroed by one memset
  int*   off    = (int*)  (ws + 196608);     // 16385 ints
  int*   r2     = (int*)  (ws + 327936);     // 2 MiB
  float* w2     = (float*)(ws + 2425088);    // 2 MiB
  unsigned short* Wt = (unsigned short*)(ws + 4522240);   // 8 MiB bf16 packed
  float* h1p    = (float*)(ws + 12910848);   // 4 * [16384][200] f32 = 52.4 MiB
  int*   rank   = (int*)  (ws + 66060288);   // 2 MiB per-edge rank
  float* g      = (float*)(ws + 93126912);   // [16384][8] f32
  unsigned short* h1b = (unsigned short*)(ws + 93651200); // [16384][200] bf16 = 6.55 MiB

  hipMemsetAsync(ws, 0, 131072, stream);     // deg + cnt = 0
  k_packdeg<<<2048,  256, 0, stream>>>(W1, Wt, ei, ew, deg, cnt, rank);
  k_scan   <<<1,    1024, 0, stream>>>(cnt, off);
  k_scatter<<<2048,  256, 0, stream>>>(ei, ew, deg, off, rank, r2, w2);
  k_gemm1  <<<512,   512, 0, stream>>>(x, Wt, h1p);
  k_reduce <<<3200,  256, 0, stream>>>(h1p, h1b);
  k_agg1   <<<16384, 256, 0, stream>>>(h1b, r2, w2, off, deg, b1, W2, g);
  k_agg2   <<<512,   256, 0, stream>>>(g, r2, w2, off, deg, b2, out);
}

// Round 19
// 380.258 us; speedup vs baseline: 1.1181x; 1.1181x over previous
//
#include <hip/hip_runtime.h>

#define N_NODES 16384
#define KDIM    16384
#define E_EDGES 524288
#define H1DIM   200
#define H2DIM   8

#define BM 128
#define BK 32
#define KSPLIT 4
#define KLEN 4096       // KDIM / KSPLIT
#define NT 128          // KLEN / BK
#define H1P_STRIDE (N_NODES * H1DIM)   // floats per K-split partial (compact, no pad)

typedef __attribute__((ext_vector_type(8))) short bf16x8;
typedef __attribute__((ext_vector_type(4))) float fx4;
typedef __attribute__((ext_vector_type(4))) unsigned int ux4;
typedef __attribute__((ext_vector_type(2))) unsigned int ux2;

__device__ __forceinline__ unsigned short f2bf(float f) {
  unsigned int u = __builtin_bit_cast(unsigned int, f);
  return (unsigned short)((u + 0x7FFFu + ((u >> 16) & 1u)) >> 16);  // RNE
}
__device__ __forceinline__ unsigned int pk2(float a, float b) {
  return (unsigned int)f2bf(a) | ((unsigned int)f2bf(b) << 16);
}
__device__ __forceinline__ float bf2f(unsigned int u) {
  return __builtin_bit_cast(float, u << 16);
}

// ---------------- W1 pack (coalesced) + edge-degree atomics + per-edge rank ----------------
// deg/cnt memset-zeroed before this kernel; self-loop +1 folded into rsqrt(deg+1) at use.
// rank[e] = edge's unique slot within its destination node's CSR segment -> scatter
// needs NO atomics.

__global__ void k_packdeg(const float* __restrict__ W1, unsigned short* __restrict__ Wt,
                          const int* __restrict__ ei, const float* __restrict__ ew,
                          float* deg, int* cnt, int* __restrict__ rank) {
  int n = threadIdx.x;            // 0..255
  int k8 = blockIdx.x;            // 0..2047
  int e = k8 * 256 + n;
  int c = ei[E_EDGES + e];
  rank[e] = atomicAdd(&cnt[c], 1);
  atomicAdd(&deg[c], ew[e]);
  unsigned short v[8];
  if (n < H1DIM) {
    const float* base = W1 + (size_t)(k8 * 8) * H1DIM + n;
#pragma unroll
    for (int i = 0; i < 8; ++i) v[i] = f2bf(base[(size_t)i * H1DIM]);
  } else {
#pragma unroll
    for (int i = 0; i < 8; ++i) v[i] = 0;
  }
  ux4 o;
  o[0] = (unsigned int)v[0] | ((unsigned int)v[1] << 16);
  o[1] = (unsigned int)v[2] | ((unsigned int)v[3] << 16);
  o[2] = (unsigned int)v[4] | ((unsigned int)v[5] << 16);
  o[3] = (unsigned int)v[6] | ((unsigned int)v[7] << 16);
  *(ux4*)(Wt + (size_t)k8 * 2048 + n * 8) = o;
}

// scan over cnt -> off
__global__ void k_scan(const int* __restrict__ cnt, int* __restrict__ off) {
  __shared__ int s[1024];
  int t = threadIdx.x;
  int base = t * 16;
  int loc[16]; int sum = 0;
#pragma unroll
  for (int i = 0; i < 16; ++i) { loc[i] = cnt[base + i]; sum += loc[i]; }
  s[t] = sum; __syncthreads();
  for (int d = 1; d < 1024; d <<= 1) {
    int v = (t >= d) ? s[t - d] : 0;
    __syncthreads();
    s[t] += v;
    __syncthreads();
  }
  int run = (t == 0) ? 0 : s[t - 1];
#pragma unroll
  for (int i = 0; i < 16; ++i) { off[base + i] = run; run += loc[i]; }
  if (t == 1023) off[N_NODES] = run;
}

// atomic-free scatter: slot = off[c] + rank[e]
__global__ void k_scatter(const int* __restrict__ ei, const float* __restrict__ ew,
                          const float* __restrict__ deg, const int* __restrict__ off,
                          const int* __restrict__ rank,
                          int* __restrict__ r2, float* __restrict__ w2) {
  int e = blockIdx.x * 256 + threadIdx.x;
  if (e < E_EDGES) {
    int r = ei[e], c = ei[E_EDGES + e];
    float w = rsqrtf(deg[r] + 1.0f) * ew[e] * rsqrtf(deg[c] + 1.0f);
    int p = off[c] + rank[e];
    r2[p] = r; w2[p] = w;
  }
}

// ---------------- GEMM1 (R17 verbatim — best verified: 381.7 us) ----------------

#define LOADA(KT, AI)                                   \
  { const float* _p = xp0 + (KT) * BK;                  \
    aR[AI][0] = *(const fx4*)_p;                        \
    aR[AI][1] = *(const fx4*)(_p + 4); }

#define STAGEB(BUF, KT)                                                                  \
  { const unsigned short* _s = wbase + (size_t)(KT) * 8192 + (size_t)t * 8;              \
    char* _d = ldsB + (BUF) * 16384 + wv * 1024;                                         \
    __builtin_amdgcn_global_load_lds((const __attribute__((address_space(1))) void*)(_s),        (__attribute__((address_space(3))) void*)(_d),        16, 0, 0); \
    __builtin_amdgcn_global_load_lds((const __attribute__((address_space(1))) void*)(_s + 4096), (__attribute__((address_space(3))) void*)(_d + 8192), 16, 0, 0); }

#define WRITEA(AI)                                          \
  { ux4 _dv;                                                \
    _dv[0] = pk2(aR[AI][0][0], aR[AI][0][1]);               \
    _dv[1] = pk2(aR[AI][0][2], aR[AI][0][3]);               \
    _dv[2] = pk2(aR[AI][1][0], aR[AI][1][1]);               \
    _dv[3] = pk2(aR[AI][1][2], aR[AI][1][3]);               \
    *(ux4*)(ldsA + (AI) * 8192 + ((akblk * 128 + am) << 4)) = _dv; }

#define COMPUTE(BUF)                                                                     \
  { const char* _pa = ldsA + (BUF) * 8192;                                               \
    const char* _pb = ldsB + (BUF) * 16384;                                              \
    bf16x8 _af[4], _bf[4];                                                               \
    _Pragma("unroll")                                                                    \
    for (int mi = 0; mi < 4; ++mi)                                                       \
      _af[mi] = *(const bf16x8*)(_pa + ((g * 128 + wm * 64 + mi * 16 + l15) << 4));      \
    _Pragma("unroll")                                                                    \
    for (int ni = 0; ni < 4; ++ni)                                                       \
      _bf[ni] = *(const bf16x8*)(_pb + ((g * 256 + wn * 64 + ni * 16 + l15) << 4));      \
    _Pragma("unroll")                                                                    \
    for (int mi = 0; mi < 4; ++mi)                                                       \
      _Pragma("unroll")                                                                  \
      for (int ni = 0; ni < 4; ++ni)                                                     \
        acc[mi][ni] = __builtin_amdgcn_mfma_f32_16x16x32_bf16(_af[mi], _bf[ni], acc[mi][ni], 0, 0, 0); }

#define SYNC_VM(N)                                          \
  __builtin_amdgcn_sched_barrier(0);                        \
  asm volatile("s_waitcnt vmcnt(" #N ")" ::: "memory");     \
  asm volatile("s_waitcnt lgkmcnt(0)" ::: "memory");        \
  __builtin_amdgcn_s_barrier();                             \
  __builtin_amdgcn_sched_barrier(0);

#define GSTEP(KT, PAR)                 \
  STAGEB((PAR) ^ 1, (KT) + 1)          \
  __builtin_amdgcn_sched_barrier(0);   \
  LOADA((KT) + 2, PAR)                 \
  __builtin_amdgcn_sched_barrier(0);   \
  COMPUTE(PAR)                         \
  WRITEA((PAR) ^ 1)                    \
  SYNC_VM(2)

__launch_bounds__(512, 4)
__global__ void k_gemm1(const float* __restrict__ x, const unsigned short* __restrict__ Wt,
                        float* __restrict__ h1p) {
  __shared__ char lds[49152];       // A: [2][8192] @0, B: [2][16384] @16384
  const int t = threadIdx.x;
  const int wv = t >> 6;
  const int wm = wv >> 2, wn = wv & 3;
  const int ln = t & 63;
  const int g = ln >> 4, l15 = ln & 15;
  const int bid = blockIdx.x;
  const int ks = bid & 3;
  const size_t m0 = (size_t)(bid >> 2) * BM;
  const int k0 = ks * KLEN;

  const int am = t >> 2;
  const int akblk = t & 3;
  const float* xp0 = x + (m0 + am) * (size_t)KDIM + k0 + akblk * 8;
  const unsigned short* wbase = Wt + (size_t)k0 * 256;

  char* ldsA = lds;
  char* ldsB = lds + 16384;

  fx4 acc[4][4] = {};
  fx4 aR[2][2];

  LOADA(0, 0)
  LOADA(1, 1)
  STAGEB(0, 0)
  WRITEA(0)
  SYNC_VM(0)

  for (int kt = 0; kt < NT - 2; kt += 2) {
    GSTEP(kt + 0, 0)
    GSTEP(kt + 1, 1)
  }

  STAGEB(1, NT - 1)
  __builtin_amdgcn_sched_barrier(0);
  COMPUTE(0)
  WRITEA(1)
  SYNC_VM(0)
  COMPUTE(1)

  // compact C-write: only cols < 200 (pad cols never materialized)
  float* outp = h1p + (size_t)ks * H1P_STRIDE;
#pragma unroll
  for (int mi = 0; mi < 4; ++mi)
#pragma unroll
    for (int ni = 0; ni < 4; ++ni) {
      int col = wn * 64 + ni * 16 + l15;
      if (col < H1DIM) {
#pragma unroll
        for (int r = 0; r < 4; ++r)
          outp[(m0 + wm * 64 + mi * 16 + g * 4 + r) * H1DIM + col] = acc[mi][ni][r];
      }
    }
}

// ---------------- reduce: pure linear stream over compact [4][16384][200] ----------------

__global__ void k_reduce(const float* __restrict__ h1p, unsigned short* __restrict__ h1b) {
  int i = blockIdx.x * 256 + threadIdx.x;   // < 819200 fx4 items
  const fx4* a = (const fx4*)h1p;
  fx4 v = a[i];
  v += a[i + 819200]; v += a[i + 1638400]; v += a[i + 2457600];
  ux2 o;
  o[0] = pk2(v[0], v[1]);
  o[1] = pk2(v[2], v[3]);
  *(ux2*)(h1b + (size_t)i * 4) = o;
}

// ---------------- layer-1 agg + bias + relu + layer-2 linear (fused; 8-way unroll) ----------------

__global__ void k_agg1(const unsigned short* __restrict__ h1b, const int* __restrict__ r2,
                       const float* __restrict__ w2, const int* __restrict__ off,
                       const float* __restrict__ deg, const float* __restrict__ b1,
                       const float* __restrict__ W2, float* __restrict__ g) {
  __shared__ float sh[H1DIM];
  __shared__ float w2s[H1DIM * H2DIM];
  __shared__ float red[256];
  int c = blockIdx.x;
  int t = threadIdx.x;
  if (t < H1DIM) {
    int p0 = off[c], p1 = off[c + 1];
    float acc = 0.0f;
    int p = p0;
    for (; p + 8 <= p1; p += 8) {       // 8-way unroll: 8 row-gathers in flight
      float a0 = 0.f, a1 = 0.f;
#pragma unroll
      for (int u = 0; u < 8; ++u) {
        int rr = r2[p + u];
        float ww = w2[p + u];
        float vv = bf2f((unsigned int)h1b[(size_t)rr * H1DIM + t]);
        if (u & 1) a1 += ww * vv; else a0 += ww * vv;
      }
      acc += a0 + a1;
    }
    for (; p < p1; ++p)
      acc += w2[p] * bf2f((unsigned int)h1b[(size_t)r2[p] * H1DIM + t]);
    float d2 = 1.0f / (deg[c] + 1.0f);    // dinv^2 exactly
    acc += d2 * bf2f((unsigned int)h1b[(size_t)c * H1DIM + t]);
    sh[t] = fmaxf(acc + b1[t], 0.0f);
  } else {
    for (int i = t - H1DIM; i < H1DIM * H2DIM; i += 256 - H1DIM) w2s[i] = W2[i];
  }
  __syncthreads();
  int jo = t & 7, kc = t >> 3;
  float part = 0.0f;
  for (int k = kc; k < H1DIM; k += 32) part += sh[k] * w2s[k * 8 + jo];
  red[t] = part;
  __syncthreads();
#pragma unroll
  for (int s = 16; s >= 1; s >>= 1) {
    if (kc < s) red[t] += red[t + s * 8];
    __syncthreads();
  }
  if (t < 8) g[(size_t)c * 8 + t] = red[t];
}

// ---------------- layer-2 aggregation + bias ----------------

__global__ void k_agg2(const float* __restrict__ g, const int* __restrict__ r2,
                       const float* __restrict__ w2, const int* __restrict__ off,
                       const float* __restrict__ deg, const float* __restrict__ b2,
                       float* __restrict__ out) {
  int t = threadIdx.x;
  int c = blockIdx.x * 32 + (t >> 3), j = t & 7;
  int p0 = off[c], p1 = off[c + 1];
  float acc = 0.0f;
  for (int p = p0; p < p1; ++p) acc += w2[p] * g[(size_t)r2[p] * 8 + j];
  float d2 = 1.0f / (deg[c] + 1.0f);
  out[(size_t)c * 8 + j] = acc + d2 * g[(size_t)c * 8 + j] + b2[j];
}

// ---------------- launch ----------------

extern "C" void kernel_launch(void* const* d_in, const int* in_sizes, int n_in,
                              void* d_out, int out_size, void* d_ws, size_t ws_size,
                              hipStream_t stream) {
  (void)in_sizes; (void)n_in; (void)out_size; (void)ws_size;
  const float* x  = (const float*)d_in[0];
  const int*   ei = (const int*)d_in[1];
  const float* ew = (const float*)d_in[2];
  const float* W1 = (const float*)d_in[3];
  const float* b1 = (const float*)d_in[4];
  const float* W2 = (const float*)d_in[5];
  const float* b2 = (const float*)d_in[6];
  float* out = (float*)d_out;
  char* ws = (char*)d_ws;

  float* deg    = (float*)(ws + 0);          // 64 KiB  } contiguous 128 KiB,
  int*   cnt    = (int*)  (ws + 65536);      // 64 KiB  } zeroed by one memset
  int*   off    = (int*)  (ws + 196608);     // 16385 ints
  int*   r2     = (int*)  (ws + 327936);     // 2 MiB
  float* w2     = (float*)(ws + 2425088);    // 2 MiB
  unsigned short* Wt = (unsigned short*)(ws + 4522240);   // 8 MiB bf16 packed
  float* h1p    = (float*)(ws + 12910848);   // 4 * [16384][200] f32 = 52.4 MiB
  int*   rank   = (int*)  (ws + 66060288);   // 2 MiB per-edge rank
  float* g      = (float*)(ws + 93126912);   // [16384][8] f32
  unsigned short* h1b = (unsigned short*)(ws + 93651200); // [16384][200] bf16 = 6.55 MiB

  hipMemsetAsync(ws, 0, 131072, stream);     // deg + cnt = 0
  k_packdeg<<<2048,  256, 0, stream>>>(W1, Wt, ei, ew, deg, cnt, rank);
  k_scan   <<<1,    1024, 0, stream>>>(cnt, off);
  k_scatter<<<2048,  256, 0, stream>>>(ei, ew, deg, off, rank, r2, w2);
  k_gemm1  <<<512,   512, 0, stream>>>(x, Wt, h1p);
  k_reduce <<<3200,  256, 0, stream>>>(h1p, h1b);
  k_agg1   <<<16384, 256, 0, stream>>>(h1b, r2, w2, off, deg, b1, W2, g);
  k_agg2   <<<512,   256, 0, stream>>>(g, r2, w2, off, deg, b2, out);
}